// Round 1
// baseline (628.273 us; speedup 1.0000x reference)
//
#include <hip/hip_runtime.h>
#include <hip/hip_bf16.h>
#include <stdint.h>

// Problem constants (from reference setup_inputs)
#define JT 5           // edge types
#define NE 150000      // edges per type
#define NC 2           // channels
#define NDIM 4096      // nodes
constexpr size_t MAT = (size_t)NDIM * NDIM;   // 16,777,216
constexpr size_t HN  = (size_t)NC * MAT;      // 33,554,432 (H element count)

typedef __bf16 bf16x8 __attribute__((ext_vector_type(8)));
typedef __bf16 bf16x4 __attribute__((ext_vector_type(4)));
typedef float  f32x4  __attribute__((ext_vector_type(4)));

// ---------------------------------------------------------------- softmax
// f1 = softmax(w1, axis=1), f2 = softmax(w2, axis=1); written to ws fbuf
// (for the scatter kernels) and to the tail of d_out (outputs 1 and 2).
__global__ void softmax_k(const float* __restrict__ w1, const float* __restrict__ w2,
                          float* __restrict__ fbuf, float* __restrict__ out_tail) {
    int t = threadIdx.x;
    if (t < 2 * NC) {
        const float* w = (t < NC) ? w1 : w2;
        int c = t % NC;
        float v[JT];
        float mx = -1e30f;
        for (int j = 0; j < JT; ++j) { v[j] = w[c * JT + j]; mx = fmaxf(mx, v[j]); }
        float s = 0.f;
        for (int j = 0; j < JT; ++j) { v[j] = expf(v[j] - mx); s += v[j]; }
        float inv = 1.0f / s;
        for (int j = 0; j < JT; ++j) {
            float f = v[j] * inv;
            fbuf[t * JT + j] = f;       // [f1(c0),f1(c1),f2(c0),f2(c1)] x 5
            out_tail[t * JT + j] = f;   // same flat order as (f1, f2) outputs
        }
    }
}

// ---------------------------------------------------------------- scatter
// Builds both channels of one weighted adjacency (A1 or A2^T) via fp32 atomics.
// transpose=1 swaps (row,col) -> builds the GEMM B operand already transposed.
__global__ void scatter_k(const int* __restrict__ ei, const float* __restrict__ ev,
                          const float* __restrict__ f, float* __restrict__ A,
                          int transpose) {
    int idx = blockIdx.x * blockDim.x + threadIdx.x;
    if (idx >= JT * NE) return;
    int j = idx / NE;
    int e = idx - j * NE;
    int r = ei[(size_t)j * 2 * NE + e];
    int c = ei[(size_t)j * 2 * NE + NE + e];
    float v = ev[idx];
    int row = transpose ? c : r;
    int col = transpose ? r : c;
    size_t off = (size_t)row * NDIM + col;
    atomicAdd(A + off,       f[j] * v);        // channel 0
    atomicAdd(A + MAT + off, f[JT + j] * v);   // channel 1
}

// ---------------------------------------------------------------- fp32 -> bf16
__global__ void cvt_k(const float4* __restrict__ in, bf16x4* __restrict__ out, int n4) {
    int stride = gridDim.x * blockDim.x;
    for (int i = blockIdx.x * blockDim.x + threadIdx.x; i < n4; i += stride) {
        float4 v = in[i];
        bf16x4 o;
        o[0] = (__bf16)v.x; o[1] = (__bf16)v.y; o[2] = (__bf16)v.z; o[3] = (__bf16)v.w;
        out[i] = o;
    }
}

// ---------------------------------------------------------------- GEMM
// H[c] = A[c] (MxK, k-contiguous) * B[c]^T where B is stored [N][K] k-contiguous.
// m97 structure: 128x128 tile, BK=32, 4 waves (2x2, 64x64 out each),
// global_load_lds width-16 staging, 2 barriers per K-step, 16x16x32 bf16 MFMA.
#define BM 128
#define BN 128
#define BK 32
#define KDIM 4096

__device__ __forceinline__ void gl_lds16(const __bf16* g, __bf16* l) {
    __builtin_amdgcn_global_load_lds(
        (const __attribute__((address_space(1))) void*)(uintptr_t)g,
        (__attribute__((address_space(3))) void*)l, 16, 0, 0);
}

__global__ __launch_bounds__(256) void gemm_k(const __bf16* __restrict__ A,
                                              const __bf16* __restrict__ B,
                                              float* __restrict__ C) {
    __shared__ __align__(16) __bf16 lA[BM * BK];   // 8 KiB
    __shared__ __align__(16) __bf16 lB[BN * BK];   // 8 KiB

    const int t    = threadIdx.x;
    const int lane = t & 63;
    const int wv   = t >> 6;          // wave id 0..3
    const int wm   = wv >> 1;         // wave row (0..1)
    const int wn   = wv & 1;          // wave col (0..1)
    const size_t matoff = (size_t)blockIdx.z * MAT;
    const size_t brow   = (size_t)blockIdx.y * BM;
    const size_t bcol   = (size_t)blockIdx.x * BN;

    // staging: thread t covers tile row (t>>2), 16B k-chunk (t&3)
    const __bf16* Abase = A + matoff + (brow + (size_t)(t >> 2)) * KDIM + (t & 3) * 8;
    const __bf16* Bbase = B + matoff + (bcol + (size_t)(t >> 2)) * KDIM + (t & 3) * 8;
    __bf16* dA0 = lA + wv * 512;      // wave-uniform LDS dest (1024 B per wave)
    __bf16* dB0 = lB + wv * 512;

    f32x4 acc[4][4];
#pragma unroll
    for (int m = 0; m < 4; ++m)
#pragma unroll
        for (int n = 0; n < 4; ++n) acc[m][n] = (f32x4){0.f, 0.f, 0.f, 0.f};

    const int koff = (lane >> 4) * 8;   // k offset of this lane's fragment

    for (int k0 = 0; k0 < KDIM; k0 += BK) {
        // stage A (2x 4KB) and B (2x 4KB) -> LDS, linear dest
        gl_lds16(Abase + k0,            dA0);
        gl_lds16(Abase + 64 * KDIM + k0, dA0 + 2048);
        gl_lds16(Bbase + k0,            dB0);
        gl_lds16(Bbase + 64 * KDIM + k0, dB0 + 2048);
        __syncthreads();   // drains vmcnt -> LDS tile ready

        bf16x8 af[4], bfr[4];
#pragma unroll
        for (int m = 0; m < 4; ++m) {
            int r = wm * 64 + m * 16 + (lane & 15);
            af[m] = *(const bf16x8*)(lA + r * BK + koff);
        }
#pragma unroll
        for (int n = 0; n < 4; ++n) {
            int r = wn * 64 + n * 16 + (lane & 15);
            bfr[n] = *(const bf16x8*)(lB + r * BK + koff);
        }
#pragma unroll
        for (int m = 0; m < 4; ++m)
#pragma unroll
            for (int n = 0; n < 4; ++n)
                acc[m][n] = __builtin_amdgcn_mfma_f32_16x16x32_bf16(af[m], bfr[n], acc[m][n], 0, 0, 0);
        __syncthreads();   // all LDS reads done before next stage overwrites
    }

    // epilogue: C/D layout (verified): col = lane&15, row = (lane>>4)*4 + reg
    float* Cc = C + matoff;
#pragma unroll
    for (int m = 0; m < 4; ++m) {
        int orow0 = (int)brow + wm * 64 + m * 16 + (lane >> 4) * 4;
#pragma unroll
        for (int n = 0; n < 4; ++n) {
            int ocol = (int)bcol + wn * 64 + n * 16 + (lane & 15);
            float* p = Cc + (size_t)orow0 * NDIM + ocol;
#pragma unroll
            for (int jj = 0; jj < 4; ++jj) p[(size_t)jj * NDIM] = acc[m][n][jj];
        }
    }
}

// ---------------------------------------------------------------- launch
extern "C" void kernel_launch(void* const* d_in, const int* in_sizes, int n_in,
                              void* d_out, int out_size, void* d_ws, size_t ws_size,
                              hipStream_t stream) {
    const int*   ei = (const int*)d_in[0];
    const float* ev = (const float*)d_in[1];
    const float* w1 = (const float*)d_in[2];
    const float* w2 = (const float*)d_in[3];
    float* out = (float*)d_out;

    // ws layout: A1 bf16 (67MB) | A2T bf16 (67MB) | fbuf (20 floats)
    char* ws = (char*)d_ws;
    __bf16* A1b  = (__bf16*)ws;
    __bf16* A2b  = (__bf16*)(ws + HN * sizeof(__bf16));
    float*  fbuf = (float*)(ws + 2 * HN * sizeof(__bf16));
    size_t needed = 2 * HN * sizeof(__bf16) + 32 * sizeof(float);
    if (ws_size < needed) return;  // distinctive failure: output stays zero

    float* scratch = out;  // reuse H region (exactly HN fp32) as scatter scratch

    // 1. softmax weights -> fbuf and d_out tail
    softmax_k<<<dim3(1), dim3(64), 0, stream>>>(w1, w2, fbuf, out + HN);

    const int nthreads = JT * NE;
    const int nb = (nthreads + 255) / 256;

    // 2-4. build A1 (channels 0,1) in fp32 scratch, convert to bf16
    hipMemsetAsync(scratch, 0, HN * sizeof(float), stream);
    scatter_k<<<dim3(nb), dim3(256), 0, stream>>>(ei, ev, fbuf, scratch, 0);
    cvt_k<<<dim3(2048), dim3(256), 0, stream>>>((const float4*)scratch, (bf16x4*)A1b, (int)(HN / 4));

    // 5-7. build A2^T in fp32 scratch, convert to bf16
    hipMemsetAsync(scratch, 0, HN * sizeof(float), stream);
    scatter_k<<<dim3(nb), dim3(256), 0, stream>>>(ei, ev, fbuf + NC * JT, scratch, 1);
    cvt_k<<<dim3(2048), dim3(256), 0, stream>>>((const float4*)scratch, (bf16x4*)A2b, (int)(HN / 4));

    // 8. H[c] = A1[c] @ A2[c]  (B operand pre-transposed)
    gemm_k<<<dim3(NDIM / BN, NDIM / BM, NC), dim3(256), 0, stream>>>(A1b, A2b, out);
}

// Round 2
// 466.851 us; speedup vs baseline: 1.3458x; 1.3458x over previous
//
#include <hip/hip_runtime.h>
#include <hip/hip_bf16.h>
#include <stdint.h>

// Problem constants (from reference setup_inputs)
#define JT 5           // edge types
#define NE 150000      // edges per type
#define NC 2           // channels
#define NDIM 4096      // nodes
#define KDIM 4096
constexpr size_t MAT = (size_t)NDIM * NDIM;   // 16,777,216
constexpr size_t HN  = (size_t)NC * MAT;      // 33,554,432 (H element count)

typedef __bf16 bf16x8 __attribute__((ext_vector_type(8)));
typedef __bf16 bf16x4 __attribute__((ext_vector_type(4)));
typedef float  f32x4  __attribute__((ext_vector_type(4)));

// ---------------------------------------------------------------- softmax
__global__ void softmax_k(const float* __restrict__ w1, const float* __restrict__ w2,
                          float* __restrict__ fbuf, float* __restrict__ out_tail) {
    int t = threadIdx.x;
    if (t < 2 * NC) {
        const float* w = (t < NC) ? w1 : w2;
        int c = t % NC;
        float v[JT];
        float mx = -1e30f;
        for (int j = 0; j < JT; ++j) { v[j] = w[c * JT + j]; mx = fmaxf(mx, v[j]); }
        float s = 0.f;
        for (int j = 0; j < JT; ++j) { v[j] = expf(v[j] - mx); s += v[j]; }
        float inv = 1.0f / s;
        for (int j = 0; j < JT; ++j) {
            float f = v[j] * inv;
            fbuf[t * JT + j] = f;
            out_tail[t * JT + j] = f;
        }
    }
}

// ---------------------------------------------------------------- scatter
__global__ void scatter_k(const int* __restrict__ ei, const float* __restrict__ ev,
                          const float* __restrict__ f, float* __restrict__ A,
                          int transpose) {
    int idx = blockIdx.x * blockDim.x + threadIdx.x;
    if (idx >= JT * NE) return;
    int j = idx / NE;
    int e = idx - j * NE;
    int r = ei[(size_t)j * 2 * NE + e];
    int c = ei[(size_t)j * 2 * NE + NE + e];
    float v = ev[idx];
    int row = transpose ? c : r;
    int col = transpose ? r : c;
    size_t off = (size_t)row * NDIM + col;
    atomicAdd(A + off,       f[j] * v);        // channel 0
    atomicAdd(A + MAT + off, f[JT + j] * v);   // channel 1
}

// ---------------------------------------------------------------- fp32 -> bf16
__global__ void cvt_k(const float4* __restrict__ in, bf16x4* __restrict__ out, int n4) {
    int stride = gridDim.x * blockDim.x;
    for (int i = blockIdx.x * blockDim.x + threadIdx.x; i < n4; i += stride) {
        float4 v = in[i];
        bf16x4 o;
        o[0] = (__bf16)v.x; o[1] = (__bf16)v.y; o[2] = (__bf16)v.z; o[3] = (__bf16)v.w;
        out[i] = o;
    }
}

// ---------------------------------------------------------------- GEMM
// 256x256 8-phase template (plain HIP port per guide §5):
//   BM=BN=256, BK=64, 8 waves (2M x 4N), per-wave out 128x64 (acc[8][4]),
//   128 KiB double-buffered LDS, counted vmcnt(2) at tile boundaries,
//   raw s_barrier + lgkmcnt(0) + setprio around 16-MFMA clusters,
//   row-XOR LDS swizzle (byte ^= (row&7)<<4): linear gl_lds dest +
//   inverse-swizzled GLOBAL source + swizzled ds_read (rule 21 involution).
#define BM 256
#define BN 256
#define BK 64
#define NT (KDIM / BK)          // 64 K-tiles
#define TILE_E (BM * BK)        // 16384 elems = 32768 bytes per matrix tile

__device__ __forceinline__ void gl_lds16(const __bf16* g, __bf16* l) {
    __builtin_amdgcn_global_load_lds(
        (const __attribute__((address_space(1))) void*)(uintptr_t)g,
        (__attribute__((address_space(3))) void*)l, 16, 0, 0);
}

// One phase: ds-read frag subtile, issue prefetch, barrier, lgkm0, 16 MFMA.
#define PHASE(MH, KS, READB, ...) do {                                            \
    _Pragma("unroll")                                                             \
    for (int i = 0; i < 4; ++i)                                                   \
        af[i] = *(const bf16x8*)(ldsAc +                                          \
            ((((rA + ((MH)*4 + i) * 16) * 128) + (KS)*64 + kb) ^ swz));           \
    if (READB) {                                                                  \
        _Pragma("unroll")                                                         \
        for (int n = 0; n < 4; ++n)                                               \
            bfr[n] = *(const bf16x8*)(ldsBc +                                     \
                ((((rB + n * 16) * 128) + (KS)*64 + kb) ^ swz));                  \
    }                                                                             \
    __VA_ARGS__;                                                                  \
    __builtin_amdgcn_s_barrier();                                                 \
    asm volatile("s_waitcnt lgkmcnt(0)" ::: "memory");                            \
    __builtin_amdgcn_s_setprio(1);                                                \
    _Pragma("unroll")                                                             \
    for (int i = 0; i < 4; ++i)                                                   \
        _Pragma("unroll")                                                         \
        for (int n = 0; n < 4; ++n)                                               \
            acc[(MH)*4 + i][n] = __builtin_amdgcn_mfma_f32_16x16x32_bf16(         \
                af[i], bfr[n], acc[(MH)*4 + i][n], 0, 0, 0);                      \
    __builtin_amdgcn_s_setprio(0);                                                \
    __builtin_amdgcn_s_barrier();                                                 \
} while (0)

__global__ __launch_bounds__(512, 2) void gemm_k(const __bf16* __restrict__ A,
                                                 const __bf16* __restrict__ B,
                                                 float* __restrict__ C) {
    // [buf0 A | buf0 B | buf1 A | buf1 B] = 4 x 32 KiB = 128 KiB
    __shared__ __align__(16) __bf16 sm[4 * TILE_E];

    const int u    = threadIdx.x;       // 0..511
    const int lane = u & 63;
    const int wv   = u >> 6;            // wave 0..7
    const int wm   = wv >> 2;           // wave M (0..1) -> 128 rows
    const int wn   = wv & 3;            // wave N (0..3) -> 64 cols
    const size_t matoff = (size_t)blockIdx.z * MAT;
    const size_t brow   = (size_t)blockIdx.y * BM;
    const size_t bcol   = (size_t)blockIdx.x * BN;

    // ---- staging geometry: a unit = 64 rows x 64 k of one matrix = one
    // gl_lds16 over 512 threads x 16B... (8 KiB) -- 2 calls? no: 64*64*2B = 8 KiB
    // = exactly one 512-thread x 16B call. 4 units per matrix per K-tile.
    const int srow = u >> 3;                       // row within unit, 0..63
    const int kc   = (u & 7) ^ (srow & 7);         // inverse-swizzled k-chunk
    const __bf16* Abase = A + matoff + (brow + srow) * KDIM + kc * 8;
    const __bf16* Bbase = B + matoff + (bcol + srow) * KDIM + kc * 8;

    char* const smb = (char*)sm;
    // LDS byte bases: Atile(buf) = smb + buf*65536 ; Btile(buf) = +32768
    auto issueA = [&](int unit, int tt) {
        const __bf16* src = Abase + (size_t)unit * 64 * KDIM + (size_t)tt * BK;
        __bf16* dst = (__bf16*)(smb + (tt & 1) * 65536 + unit * 8192 + wv * 1024);
        gl_lds16(src, dst);
    };
    auto issueB = [&](int unit, int tt) {
        const __bf16* src = Bbase + (size_t)unit * 64 * KDIM + (size_t)tt * BK;
        __bf16* dst = (__bf16*)(smb + (tt & 1) * 65536 + 32768 + unit * 8192 + wv * 1024);
        gl_lds16(src, dst);
    };

    // ---- fragment read geometry (swizzled ds_read_b128)
    const int rA  = wm * 128 + (lane & 15);   // A row base (add m*16)
    const int rB  = wn * 64  + (lane & 15);   // B row base (add n*16)
    const int kb  = (lane >> 4) * 16;         // byte offset of lane's k-octet
    const int swz = (lane & 7) << 4;          // XOR swizzle mask

    f32x4 acc[8][4];
#pragma unroll
    for (int m = 0; m < 8; ++m)
#pragma unroll
        for (int n = 0; n < 4; ++n) acc[m][n] = (f32x4){0.f, 0.f, 0.f, 0.f};

    bf16x8 af[4], bfr[4];

    // ---- prologue: stage all 8 units of tile 0 into buf0
#pragma unroll
    for (int i = 0; i < 4; ++i) issueA(i, 0);
#pragma unroll
    for (int i = 0; i < 4; ++i) issueB(i, 0);

    for (int t = 0; t < NT; ++t) {
        const char* ldsAc = smb + (t & 1) * 65536;
        const char* ldsBc = ldsAc + 32768;
        const int nxt = t + 1;
        const bool hasNext = nxt < NT;

        // boundary: issue first pair of next tile, then counted gate on this tile
        if (hasNext) {
            issueA(0, nxt); issueA(1, nxt);
            asm volatile("s_waitcnt vmcnt(2)" ::: "memory");
        } else {
            asm volatile("s_waitcnt vmcnt(0)" ::: "memory");
        }
        __builtin_amdgcn_s_barrier();
        asm volatile("" ::: "memory");   // compiler fence: no LDS read hoists above gate

        PHASE(0, 0, true,  if (hasNext) { issueA(2, nxt); issueA(3, nxt);
                                          issueB(0, nxt); issueB(1, nxt); });
        PHASE(1, 0, false, if (hasNext) { issueB(2, nxt); issueB(3, nxt); });
        PHASE(0, 1, true,  );
        PHASE(1, 1, false, );
    }

    // ---- epilogue: C/D layout col = lane&15, row = (lane>>4)*4 + reg
    float* Cc = C + matoff;
#pragma unroll
    for (int m = 0; m < 8; ++m) {
        int orow0 = (int)brow + wm * 128 + m * 16 + (lane >> 4) * 4;
#pragma unroll
        for (int n = 0; n < 4; ++n) {
            int ocol = (int)bcol + wn * 64 + n * 16 + (lane & 15);
            float* p = Cc + (size_t)orow0 * NDIM + ocol;
#pragma unroll
            for (int jj = 0; jj < 4; ++jj) p[(size_t)jj * NDIM] = acc[m][n][jj];
        }
    }
}

// ---------------------------------------------------------------- launch
extern "C" void kernel_launch(void* const* d_in, const int* in_sizes, int n_in,
                              void* d_out, int out_size, void* d_ws, size_t ws_size,
                              hipStream_t stream) {
    const int*   ei = (const int*)d_in[0];
    const float* ev = (const float*)d_in[1];
    const float* w1 = (const float*)d_in[2];
    const float* w2 = (const float*)d_in[3];
    float* out = (float*)d_out;

    // ws layout: A1 bf16 (67MB) | A2T bf16 (67MB) | fbuf (20 floats)
    char* ws = (char*)d_ws;
    __bf16* A1b  = (__bf16*)ws;
    __bf16* A2b  = (__bf16*)(ws + HN * sizeof(__bf16));
    float*  fbuf = (float*)(ws + 2 * HN * sizeof(__bf16));
    size_t needed = 2 * HN * sizeof(__bf16) + 32 * sizeof(float);
    if (ws_size < needed) return;

    float* scratch = out;  // reuse H region (exactly HN fp32) as scatter scratch

    softmax_k<<<dim3(1), dim3(64), 0, stream>>>(w1, w2, fbuf, out + HN);

    const int nthreads = JT * NE;
    const int nb = (nthreads + 255) / 256;

    hipMemsetAsync(scratch, 0, HN * sizeof(float), stream);
    scatter_k<<<dim3(nb), dim3(256), 0, stream>>>(ei, ev, fbuf, scratch, 0);
    cvt_k<<<dim3(2048), dim3(256), 0, stream>>>((const float4*)scratch, (bf16x4*)A1b, (int)(HN / 4));

    hipMemsetAsync(scratch, 0, HN * sizeof(float), stream);
    scatter_k<<<dim3(nb), dim3(256), 0, stream>>>(ei, ev, fbuf + NC * JT, scratch, 1);
    cvt_k<<<dim3(2048), dim3(256), 0, stream>>>((const float4*)scratch, (bf16x4*)A2b, (int)(HN / 4));

    gemm_k<<<dim3(NDIM / BN, NDIM / BM, NC), dim3(512), 0, stream>>>(A1b, A2b, out);
}